// Round 4
// baseline (2399.935 us; speedup 1.0000x reference)
//
#include <hip/hip_runtime.h>
#include <math.h>

#define N_NODES 50000
#define N_EDGES 800000
#define HID 128
#define OUTC 64
#define NLAYERS 8
#define SLICE_C 16

#define SCAN_B 64
#define SCAN_T 256
#define SCAN_C 4   // 64*256*4 = 65536 >= 50000

typedef float f4v __attribute__((ext_vector_type(4)));
typedef float f2v __attribute__((ext_vector_type(2)));

// ---------------- CSR build ----------------

__global__ void k_zero(int* __restrict__ p, int n) {
    int i = blockIdx.x * blockDim.x + threadIdx.x;
    if (i < n) p[i] = 0;
}

__global__ void k_count(const int* __restrict__ dst, int* __restrict__ deg, int E) {
    int e = blockIdx.x * blockDim.x + threadIdx.x;
    if (e < E) atomicAdd(&deg[dst[e]], 1);
}

__global__ __launch_bounds__(SCAN_T) void k_scanA(const int* __restrict__ deg, int* __restrict__ bsum) {
    __shared__ int red[SCAN_T];
    const int t = threadIdx.x, b = blockIdx.x;
    const int g = b * SCAN_T + t;
    int lo = g * SCAN_C; if (lo > N_NODES) lo = N_NODES;
    int hi = lo + SCAN_C; if (hi > N_NODES) hi = N_NODES;
    int s = 0;
    for (int i = lo; i < hi; i++) s += deg[i];
    red[t] = s;
    __syncthreads();
    for (int d = SCAN_T / 2; d > 0; d >>= 1) {
        if (t < d) red[t] += red[t + d];
        __syncthreads();
    }
    if (t == 0) bsum[b] = red[0];
}

__global__ __launch_bounds__(SCAN_T) void k_scanB(int* __restrict__ cur, int* __restrict__ off,
                                                  const int* __restrict__ bsum) {
    __shared__ int pre[SCAN_T];
    __shared__ int baseSh;
    const int t = threadIdx.x, b = blockIdx.x;
    const int g = b * SCAN_T + t;
    int lo = g * SCAN_C; if (lo > N_NODES) lo = N_NODES;
    int hi = lo + SCAN_C; if (hi > N_NODES) hi = N_NODES;
    int s = 0;
    for (int i = lo; i < hi; i++) s += cur[i];
    pre[t] = s;
    if (t == 0) {
        int acc = 0;
        for (int j = 0; j < b; j++) acc += bsum[j];
        baseSh = acc;
    }
    __syncthreads();
    for (int d = 1; d < SCAN_T; d <<= 1) {
        int v = (t >= d) ? pre[t - d] : 0;
        __syncthreads();
        pre[t] += v;
        __syncthreads();
    }
    int running = baseSh + pre[t] - s;
    for (int i = lo; i < hi; i++) {
        int d = cur[i];
        off[i] = running;
        cur[i] = running;
        running += d;
        if (i == N_NODES - 1) off[N_NODES] = running;
    }
}

// scatter edges into CSR order; src compressed to u16 (N_NODES < 65536), weight f32
__global__ void k_scatter(const int* __restrict__ src, const int* __restrict__ dst,
                          const float* __restrict__ w, int* __restrict__ cursor,
                          unsigned short* __restrict__ e_src, float* __restrict__ e_w, int E) {
    int e = blockIdx.x * blockDim.x + threadIdx.x;
    if (e < E) {
        int d = dst[e];
        int pos = atomicAdd(&cursor[d], 1);
        e_src[pos] = (unsigned short)src[e];
        e_w[pos]   = w[e];
    }
}

// ---------------- channel-sliced SPMM ----------------
// feats: sliced layout [NS][N_NODES][16]. blockIdx%8 selects the slice so that the
// default round-robin block->XCD dispatch pins each 3.2MB slice into one XCD's L2.
// (Assumption is perf-only; any block can read any slice correctly.)
// Wave layout: 64 lanes = 4 edge-groups x 16 channels; 4 edges processed per step.
// MODE 0 (NS=8): h = relu(acc + b_in[ch]) -> o1=h_sliced, o2=x0_sliced
// MODE 1 (NS=8): t[n][ch] = 0.5*acc + 0.5*x0_sliced   (t row-major [N][128])
// MODE 2 (NS=4): out[n*64+ch] = acc + b_out[ch]
template <int MODE, int NS>
__global__ __launch_bounds__(256) void k_spmm_sl(
    const int* __restrict__ off, const unsigned short* __restrict__ e_src,
    const float* __restrict__ e_w, const float* __restrict__ feats,
    const float* __restrict__ aux, float* __restrict__ o1, float* __restrict__ o2)
{
    const int slot = blockIdx.x & 7;
    const int tile = blockIdx.x >> 3;
    int s, node0;
    if constexpr (NS == 8) { s = slot; node0 = tile * 32; }
    else                   { s = slot & 3; node0 = tile * 64 + (slot >> 2) * 32; }

    const int wave = threadIdx.x >> 6;
    const int lane = threadIdx.x & 63;
    const int g    = lane >> 4;    // edge group 0..3
    const int ch   = lane & 15;    // channel within slice
    const float* __restrict__ fsl = feats + (size_t)s * N_NODES * SLICE_C;

    #pragma unroll 1
    for (int i = 0; i < 8; i++) {
        const int node = node0 + wave * 8 + i;
        if (node >= N_NODES) return;
        const int lo = off[node], hi = off[node + 1];

        float acc = 0.f;
        for (int base = lo; base < hi; base += 64) {
            const int cnt = min(hi - base, 64);
            int   sv = 0;
            float wv = 0.f;
            if (lane < cnt) {
                sv = (int)__builtin_nontemporal_load(&e_src[base + lane]);
                wv = __builtin_nontemporal_load(&e_w[base + lane]);
            }
            const int kmax = (cnt + 3) & ~3;
            for (int j = 0; j < kmax; j += 4) {
                int   idx = j + g;             // uniform within each 16-lane group
                int   ss  = __shfl(sv, idx);
                float ww  = __shfl(wv, idx);   // lanes >= cnt padded with w=0
                float v   = fsl[(size_t)ss * SLICE_C + ch];
                acc = fmaf(ww, v, acc);
            }
        }
        // sum the 4 edge-groups: lanes differing in bits 4,5 hold same channel
        acc += __shfl_xor(acc, 16);
        acc += __shfl_xor(acc, 32);

        if (lane < 16) {
            if constexpr (MODE == 0) {
                float r = fmaxf(acc + aux[s * 16 + ch], 0.f);
                size_t p = (size_t)s * N_NODES * SLICE_C + (size_t)node * SLICE_C + ch;
                __builtin_nontemporal_store(r, &o1[p]);
                __builtin_nontemporal_store(r, &o2[p]);
            } else if constexpr (MODE == 1) {
                float x0v = __builtin_nontemporal_load(
                    &aux[(size_t)s * N_NODES * SLICE_C + (size_t)node * SLICE_C + ch]);
                float r = 0.5f * acc + 0.5f * x0v;
                __builtin_nontemporal_store(r, &o1[(size_t)node * HID + s * 16 + ch]);
            } else {
                o1[(size_t)node * OUTC + s * 16 + ch] = acc + aux[s * 16 + ch];
            }
        }
    }
}

// ---------------- GEMM kernels ----------------
// input GEMM: z = x @ W_in ; x row-major [N][128], z written SLICED [8][N][16]
__global__ __launch_bounds__(256) void k_gemm_in(
    const float* __restrict__ A, const float* __restrict__ W, float* __restrict__ zS)
{
    __shared__ float As[32][128];
    const int tid = threadIdx.x;
    const int row0 = blockIdx.x * 32;
    {
        const f4v* srcp = (const f4v*)(A + (size_t)row0 * 128);
        f4v* dl = (f4v*)(&As[0][0]);
        #pragma unroll
        for (int it = 0; it < 4; it++) {
            int idx = tid + it * 256;
            int r = idx >> 5;
            f4v v = {0.f, 0.f, 0.f, 0.f};
            if (row0 + r < N_NODES) v = __builtin_nontemporal_load(&srcp[idx]);
            dl[idx] = v;
        }
    }
    __syncthreads();

    const int rg = tid >> 5;
    const int c0 = (tid & 31) * 4;
    float acc[4][4];
    #pragma unroll
    for (int i = 0; i < 4; i++)
        #pragma unroll
        for (int j = 0; j < 4; j++) acc[i][j] = 0.f;

    #pragma unroll 4
    for (int k = 0; k < 128; k++) {
        float a0 = As[rg * 4 + 0][k], a1 = As[rg * 4 + 1][k];
        float a2 = As[rg * 4 + 2][k], a3 = As[rg * 4 + 3][k];
        float4 wv = *(const float4*)(W + (size_t)k * 128 + c0);
        float w[4] = {wv.x, wv.y, wv.z, wv.w};
        #pragma unroll
        for (int j = 0; j < 4; j++) {
            acc[0][j] = fmaf(a0, w[j], acc[0][j]);
            acc[1][j] = fmaf(a1, w[j], acc[1][j]);
            acc[2][j] = fmaf(a2, w[j], acc[2][j]);
            acc[3][j] = fmaf(a3, w[j], acc[3][j]);
        }
    }

    const int sl = c0 >> 4, co = c0 & 15;
    float* ob = zS + (size_t)sl * N_NODES * SLICE_C + co;
    #pragma unroll
    for (int i = 0; i < 4; i++) {
        int r = row0 + rg * 4 + i;
        if (r < N_NODES) {
            f4v o = {acc[i][0], acc[i][1], acc[i][2], acc[i][3]};
            __builtin_nontemporal_store(o, (f4v*)(ob + (size_t)r * SLICE_C));
        }
    }
}

// layer GEMM: h = relu((1-beta)*t + beta*(t @ W)); t row-major [N][128]; h written SLICED
__global__ __launch_bounds__(256) void k_gemm_layer(
    const float* __restrict__ T, const float* __restrict__ W,
    float* __restrict__ hS, float beta)
{
    __shared__ float As[32][128];
    const int tid = threadIdx.x;
    const int row0 = blockIdx.x * 32;
    {
        const f4v* srcp = (const f4v*)(T + (size_t)row0 * 128);
        f4v* dl = (f4v*)(&As[0][0]);
        #pragma unroll
        for (int it = 0; it < 4; it++) {
            int idx = tid + it * 256;
            int r = idx >> 5;
            f4v v = {0.f, 0.f, 0.f, 0.f};
            if (row0 + r < N_NODES) v = __builtin_nontemporal_load(&srcp[idx]);
            dl[idx] = v;
        }
    }
    __syncthreads();

    const int rg = tid >> 5;
    const int c0 = (tid & 31) * 4;
    float acc[4][4];
    #pragma unroll
    for (int i = 0; i < 4; i++)
        #pragma unroll
        for (int j = 0; j < 4; j++) acc[i][j] = 0.f;

    #pragma unroll 4
    for (int k = 0; k < 128; k++) {
        float a0 = As[rg * 4 + 0][k], a1 = As[rg * 4 + 1][k];
        float a2 = As[rg * 4 + 2][k], a3 = As[rg * 4 + 3][k];
        float4 wv = *(const float4*)(W + (size_t)k * 128 + c0);
        float w[4] = {wv.x, wv.y, wv.z, wv.w};
        #pragma unroll
        for (int j = 0; j < 4; j++) {
            acc[0][j] = fmaf(a0, w[j], acc[0][j]);
            acc[1][j] = fmaf(a1, w[j], acc[1][j]);
            acc[2][j] = fmaf(a2, w[j], acc[2][j]);
            acc[3][j] = fmaf(a3, w[j], acc[3][j]);
        }
    }

    const float omb = 1.f - beta;
    const int sl = c0 >> 4, co = c0 & 15;
    float* ob = hS + (size_t)sl * N_NODES * SLICE_C + co;
    #pragma unroll
    for (int i = 0; i < 4; i++) {
        int r = row0 + rg * 4 + i;
        if (r < N_NODES) {
            f4v o;
            #pragma unroll
            for (int j = 0; j < 4; j++) {
                float t = As[rg * 4 + i][c0 + j];
                o[j] = fmaxf(omb * t + beta * acc[i][j], 0.f);
            }
            __builtin_nontemporal_store(o, (f4v*)(ob + (size_t)r * SLICE_C));
        }
    }
}

// output GEMM: y = h @ W_out ; h SLICED [8][N][16], y written SLICED-4 [4][N][16]
__global__ __launch_bounds__(256) void k_gemm_out(
    const float* __restrict__ hS, const float* __restrict__ W, float* __restrict__ y4)
{
    __shared__ float As[32][128];
    const int tid = threadIdx.x;
    const int row0 = blockIdx.x * 32;
    {
        f4v* dl = (f4v*)(&As[0][0]);
        #pragma unroll
        for (int it = 0; it < 4; it++) {
            int idx = tid + it * 256;
            int r = idx >> 5, c4 = idx & 31;          // c4: which float4 chunk of the 128 cols
            int sl = c4 >> 2, co4 = c4 & 3;
            f4v v = {0.f, 0.f, 0.f, 0.f};
            if (row0 + r < N_NODES)
                v = __builtin_nontemporal_load(
                    (const f4v*)(hS + (size_t)sl * N_NODES * SLICE_C + (size_t)(row0 + r) * SLICE_C + co4 * 4));
            dl[idx] = v;
        }
    }
    __syncthreads();

    const int rg = tid >> 5;
    const int c0 = (tid & 31) * 2;
    float acc[4][2];
    #pragma unroll
    for (int i = 0; i < 4; i++) { acc[i][0] = 0.f; acc[i][1] = 0.f; }

    #pragma unroll 4
    for (int k = 0; k < 128; k++) {
        float a0 = As[rg * 4 + 0][k], a1 = As[rg * 4 + 1][k];
        float a2 = As[rg * 4 + 2][k], a3 = As[rg * 4 + 3][k];
        float2 wv = *(const float2*)(W + (size_t)k * OUTC + c0);
        acc[0][0] = fmaf(a0, wv.x, acc[0][0]); acc[0][1] = fmaf(a0, wv.y, acc[0][1]);
        acc[1][0] = fmaf(a1, wv.x, acc[1][0]); acc[1][1] = fmaf(a1, wv.y, acc[1][1]);
        acc[2][0] = fmaf(a2, wv.x, acc[2][0]); acc[2][1] = fmaf(a2, wv.y, acc[2][1]);
        acc[3][0] = fmaf(a3, wv.x, acc[3][0]); acc[3][1] = fmaf(a3, wv.y, acc[3][1]);
    }

    const int sl = c0 >> 4, co = c0 & 15;
    float* ob = y4 + (size_t)sl * N_NODES * SLICE_C + co;
    #pragma unroll
    for (int i = 0; i < 4; i++) {
        int r = row0 + rg * 4 + i;
        if (r < N_NODES) {
            f2v o = {acc[i][0], acc[i][1]};
            __builtin_nontemporal_store(o, (f2v*)(ob + (size_t)r * SLICE_C));
        }
    }
}

// ---------------- launch ----------------

extern "C" void kernel_launch(void* const* d_in, const int* in_sizes, int n_in,
                              void* d_out, int out_size, void* d_ws, size_t ws_size,
                              hipStream_t stream)
{
    const float* x     = (const float*)d_in[0];
    const int*   ei    = (const int*)d_in[1];
    const float* ew    = (const float*)d_in[2];
    const float* W_in  = (const float*)d_in[3];
    const float* b_in  = (const float*)d_in[4];
    const float* W_lay = (const float*)d_in[5];
    const float* W_out = (const float*)d_in[6];
    const float* b_out = (const float*)d_in[7];
    float* out = (float*)d_out;

    const int* src = ei;
    const int* dst = ei + N_EDGES;

    char* p = (char*)d_ws;
    auto alloc = [&](size_t bytes) -> char* {
        char* q = p;
        p += (bytes + 255) & ~(size_t)255;
        return q;
    };
    int*            cursor = (int*)alloc((size_t)N_NODES * 4);
    int*            off    = (int*)alloc((size_t)(N_NODES + 1) * 4);
    unsigned short* e_src  = (unsigned short*)alloc((size_t)N_EDGES * 2);
    float*          e_w    = (float*)alloc((size_t)N_EDGES * 4);
    int*            bsum   = (int*)alloc((size_t)SCAN_B * 4);
    float*          bufA   = (float*)alloc((size_t)N_NODES * HID * 4);  // z_sliced / t / y4
    float*          bufH1  = (float*)alloc((size_t)N_NODES * HID * 4);  // h sliced
    float*          bufH2  = (float*)alloc((size_t)N_NODES * HID * 4);  // h sliced
    float*          bufX0  = (float*)alloc((size_t)N_NODES * HID * 4);  // x0 sliced

    // CSR build
    k_zero<<<(N_NODES + 255) / 256, 256, 0, stream>>>(cursor, N_NODES);
    k_count<<<(N_EDGES + 255) / 256, 256, 0, stream>>>(dst, cursor, N_EDGES);
    k_scanA<<<SCAN_B, SCAN_T, 0, stream>>>(cursor, bsum);
    k_scanB<<<SCAN_B, SCAN_T, 0, stream>>>(cursor, off, bsum);
    k_scatter<<<(N_EDGES + 255) / 256, 256, 0, stream>>>(src, dst, ew, cursor, e_src, e_w, N_EDGES);

    const int gemmGrid  = (N_NODES + 31) / 32;        // 1563
    const int spmm8Grid = ((N_NODES + 31) / 32) * 8;  // 12504
    const int spmm4Grid = ((N_NODES + 63) / 64) * 8;  // 6256

    // z = x @ W_in -> bufA (sliced)
    k_gemm_in<<<gemmGrid, 256, 0, stream>>>(x, W_in, bufA);
    // h = relu(spmm(z) + b_in) -> bufH1 (sliced), copy -> bufX0 (sliced)
    k_spmm_sl<0, 8><<<spmm8Grid, 256, 0, stream>>>(off, e_src, e_w, bufA, b_in, bufH1, bufX0);

    float* hin = bufH1;
    float* hout = bufH2;
    for (int l = 0; l < NLAYERS; l++) {
        float beta = logf(1.0f / (float)(l + 1) + 1.0f);
        // t = 0.5*spmm(h) + 0.5*x0 -> bufA (row-major)
        k_spmm_sl<1, 8><<<spmm8Grid, 256, 0, stream>>>(off, e_src, e_w, hin, bufX0, bufA, nullptr);
        // h' = relu((1-beta)*t + beta*(t@W_l)) -> hout (sliced)
        k_gemm_layer<<<gemmGrid, 256, 0, stream>>>(bufA, W_lay + (size_t)l * HID * HID, hout, beta);
        float* tmp = hin; hin = hout; hout = tmp;
    }

    // y = h @ W_out -> bufA (sliced-4)
    k_gemm_out<<<gemmGrid, 256, 0, stream>>>(hin, W_out, bufA);
    // out = spmm(y) + b_out
    k_spmm_sl<2, 4><<<spmm4Grid, 256, 0, stream>>>(off, e_src, e_w, bufA, b_out, out, nullptr);
}

// Round 6
// 792.729 us; speedup vs baseline: 3.0274x; 3.0274x over previous
//
#include <hip/hip_runtime.h>
#include <math.h>

#define N_NODES 50000
#define N_EDGES 800000
#define HID 128
#define OUTC 64
#define NLAYERS 8

#define SCAN_B 64
#define SCAN_T 256
#define SCAN_C 4   // 64*256*4 = 65536 >= 50000

// ---------------- bf16 helpers (manual, RNE) ----------------

__device__ __forceinline__ float bfloat_lo(unsigned int u) {           // low 16 bits -> float
    return __int_as_float((int)(u << 16));
}
__device__ __forceinline__ float bfloat_hi(unsigned int u) {           // high 16 bits -> float
    return __int_as_float((int)(u & 0xFFFF0000u));
}
__device__ __forceinline__ unsigned int f2bf(float f) {                // RNE to bf16 (as u16)
    unsigned int u = (unsigned int)__float_as_int(f);
    return (u + 0x7FFFu + ((u >> 16) & 1u)) >> 16;
}
__device__ __forceinline__ unsigned int pack2bf(float a, float b) {    // [b|a]
    return f2bf(a) | (f2bf(b) << 16);
}

// ---------------- CSR build ----------------

__global__ void k_zero(int* __restrict__ p, int n) {
    int i = blockIdx.x * blockDim.x + threadIdx.x;
    if (i < n) p[i] = 0;
}

__global__ void k_count(const int* __restrict__ dst, int* __restrict__ deg, int E) {
    int e = blockIdx.x * blockDim.x + threadIdx.x;
    if (e < E) atomicAdd(&deg[dst[e]], 1);
}

__global__ __launch_bounds__(SCAN_T) void k_scanA(const int* __restrict__ deg, int* __restrict__ bsum) {
    __shared__ int red[SCAN_T];
    const int t = threadIdx.x, b = blockIdx.x;
    const int g = b * SCAN_T + t;
    int lo = g * SCAN_C; if (lo > N_NODES) lo = N_NODES;
    int hi = lo + SCAN_C; if (hi > N_NODES) hi = N_NODES;
    int s = 0;
    for (int i = lo; i < hi; i++) s += deg[i];
    red[t] = s;
    __syncthreads();
    for (int d = SCAN_T / 2; d > 0; d >>= 1) {
        if (t < d) red[t] += red[t + d];
        __syncthreads();
    }
    if (t == 0) bsum[b] = red[0];
}

__global__ __launch_bounds__(SCAN_T) void k_scanB(int* __restrict__ cur, int* __restrict__ off,
                                                  const int* __restrict__ bsum) {
    __shared__ int pre[SCAN_T];
    __shared__ int baseSh;
    const int t = threadIdx.x, b = blockIdx.x;
    const int g = b * SCAN_T + t;
    int lo = g * SCAN_C; if (lo > N_NODES) lo = N_NODES;
    int hi = lo + SCAN_C; if (hi > N_NODES) hi = N_NODES;
    int s = 0;
    for (int i = lo; i < hi; i++) s += cur[i];
    pre[t] = s;
    if (t == 0) {
        int acc = 0;
        for (int j = 0; j < b; j++) acc += bsum[j];
        baseSh = acc;
    }
    __syncthreads();
    for (int d = 1; d < SCAN_T; d <<= 1) {
        int v = (t >= d) ? pre[t - d] : 0;
        __syncthreads();
        pre[t] += v;
        __syncthreads();
    }
    int running = baseSh + pre[t] - s;
    for (int i = lo; i < hi; i++) {
        int d = cur[i];
        off[i] = running;
        cur[i] = running;
        running += d;
        if (i == N_NODES - 1) off[N_NODES] = running;
    }
}

__global__ void k_scatter(const int* __restrict__ src, const int* __restrict__ dst,
                          const float* __restrict__ w, int* __restrict__ cursor,
                          int2* __restrict__ ep, int E) {
    int e = blockIdx.x * blockDim.x + threadIdx.x;
    if (e < E) {
        int d = dst[e];
        int pos = atomicAdd(&cursor[d], 1);
        ep[pos] = make_int2(src[e], __float_as_int(w[e]));
    }
}

// ---------------- gather helpers (lane-parallel edge fetch + shfl broadcast) ----------------

// fp32 features, 128 ch, lane covers ch c=lane*2 (float2 loads)
__device__ __forceinline__ void gatherF2(const int2* __restrict__ ep, int lo, int hi,
                                         const float* __restrict__ feats, int c,
                                         float& ax, float& ay)
{
    const int lane = threadIdx.x & 63;
    for (int base = lo; base < hi; base += 64) {
        const int cnt = min(hi - base, 64);
        int2 ev = make_int2(0, 0);
        if (lane < cnt) ev = ep[base + lane];
        int j = 0;
        for (; j + 8 <= cnt; j += 8) {
            int s0 = __shfl(ev.x, j + 0), s1 = __shfl(ev.x, j + 1);
            int s2 = __shfl(ev.x, j + 2), s3 = __shfl(ev.x, j + 3);
            int s4 = __shfl(ev.x, j + 4), s5 = __shfl(ev.x, j + 5);
            int s6 = __shfl(ev.x, j + 6), s7 = __shfl(ev.x, j + 7);
            float w0 = __int_as_float(__shfl(ev.y, j + 0));
            float w1 = __int_as_float(__shfl(ev.y, j + 1));
            float w2 = __int_as_float(__shfl(ev.y, j + 2));
            float w3 = __int_as_float(__shfl(ev.y, j + 3));
            float w4 = __int_as_float(__shfl(ev.y, j + 4));
            float w5 = __int_as_float(__shfl(ev.y, j + 5));
            float w6 = __int_as_float(__shfl(ev.y, j + 6));
            float w7 = __int_as_float(__shfl(ev.y, j + 7));
            float2 v0 = *(const float2*)(feats + (size_t)s0 * 128 + c);
            float2 v1 = *(const float2*)(feats + (size_t)s1 * 128 + c);
            float2 v2 = *(const float2*)(feats + (size_t)s2 * 128 + c);
            float2 v3 = *(const float2*)(feats + (size_t)s3 * 128 + c);
            float2 v4 = *(const float2*)(feats + (size_t)s4 * 128 + c);
            float2 v5 = *(const float2*)(feats + (size_t)s5 * 128 + c);
            float2 v6 = *(const float2*)(feats + (size_t)s6 * 128 + c);
            float2 v7 = *(const float2*)(feats + (size_t)s7 * 128 + c);
            ax = fmaf(w0, v0.x, ax); ay = fmaf(w0, v0.y, ay);
            ax = fmaf(w1, v1.x, ax); ay = fmaf(w1, v1.y, ay);
            ax = fmaf(w2, v2.x, ax); ay = fmaf(w2, v2.y, ay);
            ax = fmaf(w3, v3.x, ax); ay = fmaf(w3, v3.y, ay);
            ax = fmaf(w4, v4.x, ax); ay = fmaf(w4, v4.y, ay);
            ax = fmaf(w5, v5.x, ax); ay = fmaf(w5, v5.y, ay);
            ax = fmaf(w6, v6.x, ax); ay = fmaf(w6, v6.y, ay);
            ax = fmaf(w7, v7.x, ax); ay = fmaf(w7, v7.y, ay);
        }
        for (; j < cnt; j++) {
            int s = __shfl(ev.x, j);
            float w = __int_as_float(__shfl(ev.y, j));
            float2 v = *(const float2*)(feats + (size_t)s * 128 + c);
            ax = fmaf(w, v.x, ax); ay = fmaf(w, v.y, ay);
        }
    }
}

// bf16 features, 128 ch: lane covers ch c=lane*2 -> one u32 load per edge (row = 64 u32)
__device__ __forceinline__ void gatherB2(const int2* __restrict__ ep, int lo, int hi,
                                         const unsigned int* __restrict__ featsU, int lane,
                                         float& ax, float& ay)
{
    for (int base = lo; base < hi; base += 64) {
        const int cnt = min(hi - base, 64);
        int2 ev = make_int2(0, 0);
        if (lane < cnt) ev = ep[base + lane];
        int j = 0;
        for (; j + 8 <= cnt; j += 8) {
            int s0 = __shfl(ev.x, j + 0), s1 = __shfl(ev.x, j + 1);
            int s2 = __shfl(ev.x, j + 2), s3 = __shfl(ev.x, j + 3);
            int s4 = __shfl(ev.x, j + 4), s5 = __shfl(ev.x, j + 5);
            int s6 = __shfl(ev.x, j + 6), s7 = __shfl(ev.x, j + 7);
            float w0 = __int_as_float(__shfl(ev.y, j + 0));
            float w1 = __int_as_float(__shfl(ev.y, j + 1));
            float w2 = __int_as_float(__shfl(ev.y, j + 2));
            float w3 = __int_as_float(__shfl(ev.y, j + 3));
            float w4 = __int_as_float(__shfl(ev.y, j + 4));
            float w5 = __int_as_float(__shfl(ev.y, j + 5));
            float w6 = __int_as_float(__shfl(ev.y, j + 6));
            float w7 = __int_as_float(__shfl(ev.y, j + 7));
            unsigned int u0 = featsU[(size_t)s0 * 64 + lane];
            unsigned int u1 = featsU[(size_t)s1 * 64 + lane];
            unsigned int u2 = featsU[(size_t)s2 * 64 + lane];
            unsigned int u3 = featsU[(size_t)s3 * 64 + lane];
            unsigned int u4 = featsU[(size_t)s4 * 64 + lane];
            unsigned int u5 = featsU[(size_t)s5 * 64 + lane];
            unsigned int u6 = featsU[(size_t)s6 * 64 + lane];
            unsigned int u7 = featsU[(size_t)s7 * 64 + lane];
            ax = fmaf(w0, bfloat_lo(u0), ax); ay = fmaf(w0, bfloat_hi(u0), ay);
            ax = fmaf(w1, bfloat_lo(u1), ax); ay = fmaf(w1, bfloat_hi(u1), ay);
            ax = fmaf(w2, bfloat_lo(u2), ax); ay = fmaf(w2, bfloat_hi(u2), ay);
            ax = fmaf(w3, bfloat_lo(u3), ax); ay = fmaf(w3, bfloat_hi(u3), ay);
            ax = fmaf(w4, bfloat_lo(u4), ax); ay = fmaf(w4, bfloat_hi(u4), ay);
            ax = fmaf(w5, bfloat_lo(u5), ax); ay = fmaf(w5, bfloat_hi(u5), ay);
            ax = fmaf(w6, bfloat_lo(u6), ax); ay = fmaf(w6, bfloat_hi(u6), ay);
            ax = fmaf(w7, bfloat_lo(u7), ax); ay = fmaf(w7, bfloat_hi(u7), ay);
        }
        for (; j < cnt; j++) {
            int s = __shfl(ev.x, j);
            float w = __int_as_float(__shfl(ev.y, j));
            unsigned int u = featsU[(size_t)s * 64 + lane];
            ax = fmaf(w, bfloat_lo(u), ax); ay = fmaf(w, bfloat_hi(u), ay);
        }
    }
}

// ---------------- input spmm: h0 = relu(spmm(z fp32) + b_in) -> h bf16 AND x0 fp32 ----------------
__global__ __launch_bounds__(256) void k_spmm_in(
    const int* __restrict__ off, const int2* __restrict__ ep,
    const float* __restrict__ z, const float* __restrict__ b_in,
    unsigned int* __restrict__ hU, float* __restrict__ x0)
{
    const int wave = threadIdx.x >> 6;
    const int lane = threadIdx.x & 63;
    const int node = blockIdx.x * 4 + wave;
    if (node >= N_NODES) return;
    const int lo = off[node], hi = off[node + 1];

    float ax = 0.f, ay = 0.f;
    const int c = lane * 2;
    gatherF2(ep, lo, hi, z, c, ax, ay);
    float r0 = fmaxf(ax + b_in[c], 0.f);
    float r1 = fmaxf(ay + b_in[c + 1], 0.f);
    float2 r; r.x = r0; r.y = r1;
    *(float2*)(x0 + (size_t)node * 128 + c) = r;
    hU[(size_t)node * 64 + lane] = pack2bf(r0, r1);
}

// ---------------- final spmm: out = spmm(y bf16) + b_out ----------------
__global__ __launch_bounds__(256) void k_spmm_out(
    const int* __restrict__ off, const int2* __restrict__ ep,
    const unsigned short* __restrict__ yB, const float* __restrict__ b_out,
    float* __restrict__ out)
{
    const int wave = threadIdx.x >> 6;
    const int lane = threadIdx.x & 63;
    const int node = blockIdx.x * 4 + wave;
    if (node >= N_NODES) return;
    const int lo = off[node], hi = off[node + 1];

    float a = 0.f;
    for (int base = lo; base < hi; base += 64) {
        const int cnt = min(hi - base, 64);
        int2 ev = make_int2(0, 0);
        if (lane < cnt) ev = ep[base + lane];
        int j = 0;
        for (; j + 8 <= cnt; j += 8) {
            int s0 = __shfl(ev.x, j + 0), s1 = __shfl(ev.x, j + 1);
            int s2 = __shfl(ev.x, j + 2), s3 = __shfl(ev.x, j + 3);
            int s4 = __shfl(ev.x, j + 4), s5 = __shfl(ev.x, j + 5);
            int s6 = __shfl(ev.x, j + 6), s7 = __shfl(ev.x, j + 7);
            float w0 = __int_as_float(__shfl(ev.y, j + 0));
            float w1 = __int_as_float(__shfl(ev.y, j + 1));
            float w2 = __int_as_float(__shfl(ev.y, j + 2));
            float w3 = __int_as_float(__shfl(ev.y, j + 3));
            float w4 = __int_as_float(__shfl(ev.y, j + 4));
            float w5 = __int_as_float(__shfl(ev.y, j + 5));
            float w6 = __int_as_float(__shfl(ev.y, j + 6));
            float w7 = __int_as_float(__shfl(ev.y, j + 7));
            float v0 = bfloat_lo((unsigned int)yB[(size_t)s0 * 64 + lane]);
            float v1 = bfloat_lo((unsigned int)yB[(size_t)s1 * 64 + lane]);
            float v2 = bfloat_lo((unsigned int)yB[(size_t)s2 * 64 + lane]);
            float v3 = bfloat_lo((unsigned int)yB[(size_t)s3 * 64 + lane]);
            float v4 = bfloat_lo((unsigned int)yB[(size_t)s4 * 64 + lane]);
            float v5 = bfloat_lo((unsigned int)yB[(size_t)s5 * 64 + lane]);
            float v6 = bfloat_lo((unsigned int)yB[(size_t)s6 * 64 + lane]);
            float v7 = bfloat_lo((unsigned int)yB[(size_t)s7 * 64 + lane]);
            a = fmaf(w0, v0, a); a = fmaf(w1, v1, a);
            a = fmaf(w2, v2, a); a = fmaf(w3, v3, a);
            a = fmaf(w4, v4, a); a = fmaf(w5, v5, a);
            a = fmaf(w6, v6, a); a = fmaf(w7, v7, a);
        }
        for (; j < cnt; j++) {
            int s = __shfl(ev.x, j);
            float w = __int_as_float(__shfl(ev.y, j));
            a = fmaf(w, bfloat_lo((unsigned int)yB[(size_t)s * 64 + lane]), a);
        }
    }
    out[(size_t)node * 64 + lane] = a + b_out[lane];
}

// ---------------- input GEMM: z = x @ W_in (fp32 row-major out) ----------------
__global__ __launch_bounds__(256) void k_gemm_in(
    const float* __restrict__ A, const float* __restrict__ W,
    float* __restrict__ z)
{
    __shared__ float As[32][128];
    const int tid = threadIdx.x;
    const int row0 = blockIdx.x * 32;
    {
        const float4* srcp = (const float4*)(A + (size_t)row0 * 128);
        float4* dl = (float4*)(&As[0][0]);
        #pragma unroll
        for (int it = 0; it < 4; it++) {
            int idx = tid + it * 256;
            int r = idx >> 5;
            float4 v = make_float4(0.f, 0.f, 0.f, 0.f);
            if (row0 + r < N_NODES) v = srcp[idx];
            dl[idx] = v;
        }
    }
    __syncthreads();

    const int rg = tid >> 5;
    const int c0 = (tid & 31) * 4;
    float acc[4][4];
    #pragma unroll
    for (int i = 0; i < 4; i++)
        #pragma unroll
        for (int j = 0; j < 4; j++) acc[i][j] = 0.f;

    #pragma unroll 4
    for (int k = 0; k < 128; k++) {
        float a0 = As[rg * 4 + 0][k], a1 = As[rg * 4 + 1][k];
        float a2 = As[rg * 4 + 2][k], a3 = As[rg * 4 + 3][k];
        float4 wv = *(const float4*)(W + (size_t)k * 128 + c0);
        float w[4] = {wv.x, wv.y, wv.z, wv.w};
        #pragma unroll
        for (int j = 0; j < 4; j++) {
            acc[0][j] = fmaf(a0, w[j], acc[0][j]);
            acc[1][j] = fmaf(a1, w[j], acc[1][j]);
            acc[2][j] = fmaf(a2, w[j], acc[2][j]);
            acc[3][j] = fmaf(a3, w[j], acc[3][j]);
        }
    }

    #pragma unroll
    for (int i = 0; i < 4; i++) {
        int r = row0 + rg * 4 + i;
        if (r < N_NODES) {
            float4 o = make_float4(acc[i][0], acc[i][1], acc[i][2], acc[i][3]);
            *(float4*)(z + (size_t)r * 128 + c0) = o;
        }
    }
}

// ---------------- fused layer ----------------
// h_out(bf16) = relu((1-beta)*t + beta*(t @ W)),  t = 0.5*spmm(h_in bf16) + 0.5*x0(fp32)
__global__ __launch_bounds__(256) void k_layer(
    const int* __restrict__ off, const int2* __restrict__ ep,
    const unsigned int* __restrict__ hU, const float* __restrict__ x0,
    const float* __restrict__ W, unsigned int* __restrict__ hOutU, float beta)
{
    __shared__ float As[32][128];
    const int tid = threadIdx.x;
    const int wave = tid >> 6, lane = tid & 63;
    const int row0 = blockIdx.x * 32;
    const int c = lane * 2;

    // phase 1: spmm -> t -> LDS (each wave: 8 nodes)
    #pragma unroll 1
    for (int i = 0; i < 8; i++) {
        const int r = wave * 8 + i;
        const int node = row0 + r;
        float ax = 0.f, ay = 0.f;
        if (node < N_NODES) {
            gatherB2(ep, off[node], off[node + 1], hU, lane, ax, ay);
            float2 x0v = *(const float2*)(x0 + (size_t)node * 128 + c);
            ax = 0.5f * ax + 0.5f * x0v.x;
            ay = 0.5f * ay + 0.5f * x0v.y;
        }
        float2 t; t.x = ax; t.y = ay;
        *(float2*)(&As[r][c]) = t;
    }
    __syncthreads();

    // phase 2: gemm + GCNII epilogue, h' written bf16
    const int rg = tid >> 5;
    const int c0 = (tid & 31) * 4;

    float acc[4][4];
    #pragma unroll
    for (int i = 0; i < 4; i++)
        #pragma unroll
        for (int j = 0; j < 4; j++) acc[i][j] = 0.f;

    #pragma unroll 4
    for (int k = 0; k < 128; k++) {
        float a0 = As[rg * 4 + 0][k], a1 = As[rg * 4 + 1][k];
        float a2 = As[rg * 4 + 2][k], a3 = As[rg * 4 + 3][k];
        float4 wv = *(const float4*)(W + (size_t)k * 128 + c0);
        float w[4] = {wv.x, wv.y, wv.z, wv.w};
        #pragma unroll
        for (int j = 0; j < 4; j++) {
            acc[0][j] = fmaf(a0, w[j], acc[0][j]);
            acc[1][j] = fmaf(a1, w[j], acc[1][j]);
            acc[2][j] = fmaf(a2, w[j], acc[2][j]);
            acc[3][j] = fmaf(a3, w[j], acc[3][j]);
        }
    }

    const float omb = 1.f - beta;
    #pragma unroll
    for (int i = 0; i < 4; i++) {
        int r = row0 + rg * 4 + i;
        if (r < N_NODES) {
            float v0 = fmaxf(omb * As[rg * 4 + i][c0 + 0] + beta * acc[i][0], 0.f);
            float v1 = fmaxf(omb * As[rg * 4 + i][c0 + 1] + beta * acc[i][1], 0.f);
            float v2 = fmaxf(omb * As[rg * 4 + i][c0 + 2] + beta * acc[i][2], 0.f);
            float v3 = fmaxf(omb * As[rg * 4 + i][c0 + 3] + beta * acc[i][3], 0.f);
            uint2 pk = make_uint2(pack2bf(v0, v1), pack2bf(v2, v3));
            *(uint2*)(hOutU + (size_t)r * 64 + (c0 >> 1)) = pk;
        }
    }
}

// ---------------- output GEMM: y(bf16) = h(bf16) @ W_out ----------------
__global__ __launch_bounds__(256) void k_gemm_out(
    const unsigned int* __restrict__ hU, const float* __restrict__ W,
    unsigned int* __restrict__ yU)
{
    __shared__ float As[32][128];
    const int tid = threadIdx.x;
    const int row0 = blockIdx.x * 32;
    {
        // 32 rows x 128 bf16 ch = 512 uint4 (8 ch each)
        const uint4* srcp = (const uint4*)hU;   // global index space
        #pragma unroll
        for (int it = 0; it < 2; it++) {
            int idx = tid + it * 256;           // 0..511
            int r = idx >> 4;                   // row within tile
            int cc = (idx & 15) * 8;            // first channel of this chunk
            uint4 v = make_uint4(0u, 0u, 0u, 0u);
            if (row0 + r < N_NODES) v = srcp[(size_t)(row0 + r) * 16 + (idx & 15)];
            As[r][cc + 0] = bfloat_lo(v.x); As[r][cc + 1] = bfloat_hi(v.x);
            As[r][cc + 2] = bfloat_lo(v.y); As[r][cc + 3] = bfloat_hi(v.y);
            As[r][cc + 4] = bfloat_lo(v.z); As[r][cc + 5] = bfloat_hi(v.z);
            As[r][cc + 6] = bfloat_lo(v.w); As[r][cc + 7] = bfloat_hi(v.w);
        }
    }
    __syncthreads();

    const int rg = tid >> 5;
    const int c0 = (tid & 31) * 2;
    float acc[4][2];
    #pragma unroll
    for (int i = 0; i < 4; i++) { acc[i][0] = 0.f; acc[i][1] = 0.f; }

    #pragma unroll 4
    for (int k = 0; k < 128; k++) {
        float a0 = As[rg * 4 + 0][k], a1 = As[rg * 4 + 1][k];
        float a2 = As[rg * 4 + 2][k], a3 = As[rg * 4 + 3][k];
        float2 wv = *(const float2*)(W + (size_t)k * OUTC + c0);
        acc[0][0] = fmaf(a0, wv.x, acc[0][0]); acc[0][1] = fmaf(a0, wv.y, acc[0][1]);
        acc[1][0] = fmaf(a1, wv.x, acc[1][0]); acc[1][1] = fmaf(a1, wv.y, acc[1][1]);
        acc[2][0] = fmaf(a2, wv.x, acc[2][0]); acc[2][1] = fmaf(a2, wv.y, acc[2][1]);
        acc[3][0] = fmaf(a3, wv.x, acc[3][0]); acc[3][1] = fmaf(a3, wv.y, acc[3][1]);
    }

    #pragma unroll
    for (int i = 0; i < 4; i++) {
        int r = row0 + rg * 4 + i;
        if (r < N_NODES) {
            yU[(size_t)r * 32 + (c0 >> 1)] = pack2bf(acc[i][0], acc[i][1]);
        }
    }
}

// ---------------- launch ----------------

extern "C" void kernel_launch(void* const* d_in, const int* in_sizes, int n_in,
                              void* d_out, int out_size, void* d_ws, size_t ws_size,
                              hipStream_t stream)
{
    const float* x     = (const float*)d_in[0];
    const int*   ei    = (const int*)d_in[1];
    const float* ew    = (const float*)d_in[2];
    const float* W_in  = (const float*)d_in[3];
    const float* b_in  = (const float*)d_in[4];
    const float* W_lay = (const float*)d_in[5];
    const float* W_out = (const float*)d_in[6];
    const float* b_out = (const float*)d_in[7];
    float* out = (float*)d_out;

    const int* src = ei;
    const int* dst = ei + N_EDGES;

    char* p = (char*)d_ws;
    auto alloc = [&](size_t bytes) -> char* {
        char* q = p;
        p += (bytes + 255) & ~(size_t)255;
        return q;
    };
    int*          cursor = (int*)alloc((size_t)N_NODES * 4);
    int*          off    = (int*)alloc((size_t)(N_NODES + 1) * 4);
    int2*         ep     = (int2*)alloc((size_t)N_EDGES * 8);
    int*          bsum   = (int*)alloc((size_t)SCAN_B * 4);
    float*        bufZ   = (float*)alloc((size_t)N_NODES * HID * 4);   // z fp32
    float*        bufX0  = (float*)alloc((size_t)N_NODES * HID * 4);   // x0 fp32
    unsigned int* hA     = (unsigned int*)alloc((size_t)N_NODES * 64 * 4); // h bf16 [N][128]
    unsigned int* hB     = (unsigned int*)alloc((size_t)N_NODES * 64 * 4);
    unsigned int* yB     = (unsigned int*)alloc((size_t)N_NODES * 32 * 4); // y bf16 [N][64]

    // CSR build
    k_zero<<<(N_NODES + 255) / 256, 256, 0, stream>>>(cursor, N_NODES);
    k_count<<<(N_EDGES + 255) / 256, 256, 0, stream>>>(dst, cursor, N_EDGES);
    k_scanA<<<SCAN_B, SCAN_T, 0, stream>>>(cursor, bsum);
    k_scanB<<<SCAN_B, SCAN_T, 0, stream>>>(cursor, off, bsum);
    k_scatter<<<(N_EDGES + 255) / 256, 256, 0, stream>>>(src, dst, ew, cursor, ep, N_EDGES);

    const int gemmGrid = (N_NODES + 31) / 32;
    const int spmmGrid = (N_NODES + 3) / 4;

    // z = x @ W_in -> bufZ (fp32)
    k_gemm_in<<<gemmGrid, 256, 0, stream>>>(x, W_in, bufZ);
    // h0 = relu(spmm(z) + b_in) -> hA (bf16), x0 (fp32)
    k_spmm_in<<<spmmGrid, 256, 0, stream>>>(off, ep, bufZ, b_in, hA, bufX0);

    unsigned int* hin = hA;
    unsigned int* hout = hB;
    for (int l = 0; l < NLAYERS; l++) {
        float beta = logf(1.0f / (float)(l + 1) + 1.0f);
        k_layer<<<gemmGrid, 256, 0, stream>>>(off, ep, hin, bufX0,
                                              W_lay + (size_t)l * HID * HID, hout, beta);
        unsigned int* tmp = hin; hin = hout; hout = tmp;
    }

    // y = h @ W_out -> yB (bf16)
    k_gemm_out<<<gemmGrid, 256, 0, stream>>>(hin, W_out, yB);
    // out = spmm(y) + b_out
    k_spmm_out<<<spmmGrid, 256, 0, stream>>>(off, ep, (const unsigned short*)yB, b_out, out);
}